// Round 5
// baseline (157.180 us; speedup 1.0000x reference)
//
#include <hip/hip_runtime.h>
#include <hip/hip_bf16.h>

#define DEVI __device__ __forceinline__

typedef __attribute__((ext_vector_type(8))) short s16x8;
typedef __attribute__((ext_vector_type(4))) short s16x4;
typedef __attribute__((ext_vector_type(4))) float f32x4;

// ---- problem constants ----
// x: (8, 384, 32, 32); heads=8, dk=32, dv=64; N=1024 tokens; Cqk=256, Cv=512
#define LOG2E 1.4426950408889634f

DEVI short f2bs(float f) {  // fp32 -> bf16 bits (RNE)
    unsigned u = __builtin_bit_cast(unsigned, f);
    unsigned r = (u + 0x7fffu + ((u >> 16) & 1u)) >> 16;
    return (short)r;
}

DEVI f32x4 mfma16(s16x8 a, s16x8 b, f32x4 c) {
    return __builtin_amdgcn_mfma_f32_16x16x32_bf16(a, b, c, 0, 0, 0);
}

// ---------------- prep: x (b,c,n) fp32 -> xt (b,n,c) bf16 ----------------
__global__ __launch_bounds__(256) void k_prep_x(const float* __restrict__ x,
                                                short* __restrict__ xt) {
    __shared__ float tile[32][33];
    const int ct = blockIdx.x, nt = blockIdx.y, b = blockIdx.z;
    const int t = threadIdx.x;
    {
        const int j = t & 31, i0 = (t >> 5) * 4;
        const float* src = x + ((size_t)b * 384 + (size_t)ct * 32) * 1024 + nt * 32;
#pragma unroll
        for (int ii = 0; ii < 4; ++ii)
            tile[i0 + ii][j] = src[(size_t)(i0 + ii) * 1024 + j];
    }
    __syncthreads();
    {
        const int ii = t & 31, j0 = (t >> 5) * 4;
        short* dst = xt + ((size_t)b * 1024 + (size_t)nt * 32) * 384 + ct * 32;
#pragma unroll
        for (int jj = 0; jj < 4; ++jj)
            dst[(size_t)(j0 + jj) * 384 + ii] = f2bs(tile[ii][j0 + jj]);
    }
}

// ---------------- prep: weights fp32 -> bf16, plus BN fold ----------------
// Q-channel BN scale/shift are folded with LOG2E so softmax exp becomes exp2.
__global__ __launch_bounds__(256) void k_prep_w(
    const float* __restrict__ wq, const float* __restrict__ wk,
    const float* __restrict__ wv, const float* __restrict__ wp,
    short* __restrict__ wqkv, short* __restrict__ wpb,
    const float* gq, const float* bq, const float* mq, const float* vq,
    const float* gk, const float* bk, const float* mk, const float* vk,
    const float* gv, const float* bv, const float* mv, const float* vv,
    const float* gp, const float* bp, const float* mp, const float* vp,
    float* s_qkv, float* t_qkv, float* s_p, float* t_p) {
    int i = blockIdx.x * 256 + threadIdx.x;
    if (i < 1024) {
        const float *g, *bb, *mm, *vv_;
        int o = i;
        float post = 1.0f;
        if (i < 256)      { g = gq; bb = bq; mm = mq; vv_ = vq; post = LOG2E; }
        else if (i < 512) { g = gk; bb = bk; mm = mk; vv_ = vk; o = i - 256; }
        else              { g = gv; bb = bv; mm = mv; vv_ = vv; o = i - 512; }
        float s = g[o] * rsqrtf(vv_[o] + 1e-5f);
        s_qkv[i] = s * post;
        t_qkv[i] = (bb[o] - mm[o] * s) * post;
        if (i < 384) {
            float sp = gp[i] * rsqrtf(vp[i] + 1e-5f);
            s_p[i] = sp;
            t_p[i] = bp[i] - mp[i] * sp;
        }
    }
    const int NQKV = 1024 * 384;
    if (i < NQKV) {
        int o = i / 384;
        float v;
        if (o < 256)      v = wq[i];
        else if (o < 512) v = wk[i - 256 * 384];
        else              v = wv[i - 512 * 384];
        wqkv[i] = f2bs(v);
    } else {
        int j = i - NQKV;
        if (j < 384 * 512) wpb[j] = f2bs(wp[j]);
    }
}

// ---------------- QKV GEMM: [1024ch x 384] x [384 x 8192] + BN, layout-split ----------------
// 64m x 128j block tile, waves 2x2 (per-wave 32x64); grid (16,64)=1024 blocks = 4/CU.
// Qw: [b][h][n][32]  Kw: [b][h][m][32]  Vw: [b][h][e][1024]
__global__ __launch_bounds__(256, 4) void k_gemm_qkv(
    const short* __restrict__ wqkv, const short* __restrict__ xt,
    const float* __restrict__ s_qkv, const float* __restrict__ t_qkv,
    short* __restrict__ Qw, short* __restrict__ Kw, short* __restrict__ Vw) {
    const int t = threadIdx.x, lane = t & 63, w = t >> 6;
    const int g = lane >> 4, l15 = lane & 15;
    const int mb = blockIdx.x, jb = blockIdx.y;
    const int m_base = mb * 64 + (w >> 1) * 32;
    const int j_base = jb * 128 + (w & 1) * 64;

    f32x4 acc[2][4];
#pragma unroll
    for (int mi = 0; mi < 2; ++mi)
#pragma unroll
        for (int ni = 0; ni < 4; ++ni) acc[mi][ni] = f32x4{0.f, 0.f, 0.f, 0.f};

    const short* Arow = wqkv + (size_t)(m_base + l15) * 384 + 8 * g;
    const short* Brow = xt + (size_t)(j_base + l15) * 384 + 8 * g;

    s16x8 a[2][2], b[2][4];
#pragma unroll
    for (int i = 0; i < 2; ++i) a[0][i] = *(const s16x8*)(Arow + (size_t)i * 16 * 384);
#pragma unroll
    for (int i = 0; i < 4; ++i) b[0][i] = *(const s16x8*)(Brow + (size_t)i * 16 * 384);

#pragma unroll
    for (int ks = 0; ks < 12; ++ks) {
        const int cur = ks & 1, nxt = cur ^ 1;
        if (ks < 11) {
#pragma unroll
            for (int i = 0; i < 2; ++i)
                a[nxt][i] = *(const s16x8*)(Arow + (size_t)i * 16 * 384 + (ks + 1) * 32);
#pragma unroll
            for (int i = 0; i < 4; ++i)
                b[nxt][i] = *(const s16x8*)(Brow + (size_t)i * 16 * 384 + (ks + 1) * 32);
        }
#pragma unroll
        for (int mi = 0; mi < 2; ++mi)
#pragma unroll
            for (int ni = 0; ni < 4; ++ni)
                acc[mi][ni] = mfma16(a[cur][mi], b[cur][ni], acc[mi][ni]);
    }

#pragma unroll
    for (int mi = 0; mi < 2; ++mi) {
        const int o0 = m_base + 16 * mi;
#pragma unroll
        for (int ni = 0; ni < 4; ++ni) {
            const int j = j_base + 16 * ni + l15;
            const int bb = j >> 10, n = j & 1023;
#pragma unroll
            for (int r = 0; r < 4; ++r) {
                const int o = o0 + 4 * g + r;
                float val = acc[mi][ni][r] * s_qkv[o] + t_qkv[o];
                short bv = f2bs(val);
                if (o0 < 256) {
                    int h = o >> 5, d = o & 31;
                    Qw[(((size_t)bb * 8 + h) * 1024 + n) * 32 + d] = bv;
                } else if (o0 < 512) {
                    int o2 = o - 256;
                    int h = o2 >> 5, d = o2 & 31;
                    Kw[(((size_t)bb * 8 + h) * 1024 + n) * 32 + d] = bv;
                } else {
                    int o2 = o - 512;
                    int h = o2 >> 6, e = o2 & 63;
                    Vw[(((size_t)bb * 8 + h) * 64 + e) * 1024 + n] = bv;
                }
            }
        }
    }
}

// ---------------- attention per (b,h): no-max softmax, 16 q-rows/wave ----------------
// grid = 64 bh * 16 rb = 1024 blocks (XCD-grouped), 4 blocks/CU, 4 waves/SIMD.
// Ow: [b][n][512] bf16, ReLU applied
__global__ __launch_bounds__(256, 4) void k_attn(const short* __restrict__ Qw,
                                                 const short* __restrict__ Kw,
                                                 const short* __restrict__ Vw,
                                                 short* __restrict__ Ow) {
    __shared__ short Plds[4][1024];  // per-wave 16 rows x 64 m bf16, XOR-swizzled
    __shared__ float Lrow[4][16];
    const int t = threadIdx.x, lane = t & 63, w = t >> 6;
    const int g = lane >> 4, l15 = lane & 15;
    // blockIdx.x = (bh&7) + 8*(rb + 16*(bh>>3)) => all 16 rb of one bh on one XCD
    const int low3 = blockIdx.x & 7;
    const int mid = blockIdx.x >> 3;
    const int rb = mid & 15;
    const int bh = ((mid >> 4) << 3) | low3;
    const int n_base = rb * 64 + w * 16;
    const short* Qb = Qw + (size_t)bh * (1024 * 32);
    const short* Kb = Kw + (size_t)bh * (1024 * 32);
    const short* Vb = Vw + (size_t)bh * (64 * 1024);
    char* Pl = (char*)Plds[w];

    const s16x8 qf = *(const s16x8*)(Qb + (size_t)(n_base + l15) * 32 + 8 * g);

    f32x4 oacc[4];
#pragma unroll
    for (int ei = 0; ei < 4; ++ei) oacc[ei] = f32x4{0.f, 0.f, 0.f, 0.f};
    float l_part = 0.f;

#pragma unroll
    for (int mt = 0; mt < 16; ++mt) {
        const int m0 = mt * 64;
        // V loads issued first (consumed at PV, covered by QK+exp)
        s16x8 vb[2][4];
#pragma unroll
        for (int ki = 0; ki < 2; ++ki)
#pragma unroll
            for (int ei = 0; ei < 4; ++ei)
                vb[ki][ei] = *(const s16x8*)(Vb + (size_t)(16 * ei + l15) * 1024 + m0 + 32 * ki + 8 * g);
        // K loads
        s16x8 kf[4];
#pragma unroll
        for (int i = 0; i < 4; ++i)
            kf[i] = *(const s16x8*)(Kb + (size_t)(m0 + 16 * i + l15) * 32 + 8 * g);
        // S^T: row m = m0+16*mik+4g+r, col n = n_base + l15
        f32x4 st[4];
#pragma unroll
        for (int mik = 0; mik < 4; ++mik)
            st[mik] = mfma16(kf[mik], qf, f32x4{0.f, 0.f, 0.f, 0.f});
        // P = exp2(S'), accumulate per-lane l partial, pack bf16 -> LDS
#pragma unroll
        for (int mik = 0; mik < 4; ++mik) {
            float p[4];
#pragma unroll
            for (int r = 0; r < 4; ++r) p[r] = __builtin_amdgcn_exp2f(st[mik][r]);
            l_part += (p[0] + p[1]) + (p[2] + p[3]);
            s16x4 pk;
#pragma unroll
            for (int r = 0; r < 4; ++r) pk[r] = f2bs(p[r]);
            const int off = (l15 * 128 + 32 * mik + 8 * g) ^ ((l15 & 7) << 4);
            *(s16x4*)(Pl + off) = pk;
        }
        // read P as A-frag (row n = l15, k = m-slots), PV
#pragma unroll
        for (int ki = 0; ki < 2; ++ki) {
            const int off = (l15 * 128 + 64 * ki + 16 * g) ^ ((l15 & 7) << 4);
            s16x8 pa = *(const s16x8*)(Pl + off);
#pragma unroll
            for (int ei = 0; ei < 4; ++ei)
                oacc[ei] = mfma16(pa, vb[ki][ei], oacc[ei]);
        }
    }

    // l reduction across g groups (lanes with same l15)
    l_part += __shfl_xor(l_part, 16, 64);
    l_part += __shfl_xor(l_part, 32, 64);
    if (g == 0) Lrow[w][l15] = l_part;
    const int b = bh >> 3, h = bh & 7;
    float li[4];
#pragma unroll
    for (int r = 0; r < 4; ++r) li[r] = __builtin_amdgcn_rcpf(Lrow[w][4 * g + r]);
#pragma unroll
    for (int ei = 0; ei < 4; ++ei) {
        const int e = 16 * ei + l15;
#pragma unroll
        for (int r = 0; r < 4; ++r) {
            const int n = n_base + 4 * g + r;
            float v = fmaxf(oacc[ei][r] * li[r], 0.f);
            Ow[((size_t)b * 1024 + n) * 512 + h * 64 + e] = f2bs(v);
        }
    }
}

// ---------------- proj GEMM: [384 x 512] x [512 x 8192] + BN -> fp32 out ----------------
// 64m x 64j block tile, waves 2x2 (per-wave 32x32); grid (6,128)=768 blocks = 3/CU.
__global__ __launch_bounds__(256, 4) void k_proj(const short* __restrict__ wpb,
                                                 const short* __restrict__ Ow,
                                                 const float* __restrict__ s_p,
                                                 const float* __restrict__ t_p,
                                                 float* __restrict__ out) {
    const int t = threadIdx.x, lane = t & 63, w = t >> 6;
    const int g = lane >> 4, l15 = lane & 15;
    const int mb = blockIdx.x, jb = blockIdx.y;
    const int m_base = mb * 64 + (w >> 1) * 32;
    const int j_base = jb * 64 + (w & 1) * 32;

    f32x4 acc[2][2];
#pragma unroll
    for (int mi = 0; mi < 2; ++mi)
#pragma unroll
        for (int ni = 0; ni < 2; ++ni) acc[mi][ni] = f32x4{0.f, 0.f, 0.f, 0.f};

    const short* Arow = wpb + (size_t)(m_base + l15) * 512 + 8 * g;
    const short* Brow = Ow + (size_t)(j_base + l15) * 512 + 8 * g;

    s16x8 a[2][2], b[2][2];
#pragma unroll
    for (int i = 0; i < 2; ++i) {
        a[0][i] = *(const s16x8*)(Arow + (size_t)i * 16 * 512);
        b[0][i] = *(const s16x8*)(Brow + (size_t)i * 16 * 512);
    }

#pragma unroll
    for (int ks = 0; ks < 16; ++ks) {
        const int cur = ks & 1, nxt = cur ^ 1;
        if (ks < 15) {
#pragma unroll
            for (int i = 0; i < 2; ++i) {
                a[nxt][i] = *(const s16x8*)(Arow + (size_t)i * 16 * 512 + (ks + 1) * 32);
                b[nxt][i] = *(const s16x8*)(Brow + (size_t)i * 16 * 512 + (ks + 1) * 32);
            }
        }
#pragma unroll
        for (int mi = 0; mi < 2; ++mi)
#pragma unroll
            for (int ni = 0; ni < 2; ++ni)
                acc[mi][ni] = mfma16(a[cur][mi], b[cur][ni], acc[mi][ni]);
    }

#pragma unroll
    for (int mi = 0; mi < 2; ++mi) {
#pragma unroll
        for (int ni = 0; ni < 2; ++ni) {
            const int j = j_base + 16 * ni + l15;
            const int bb = j >> 10, n = j & 1023;
#pragma unroll
            for (int r = 0; r < 4; ++r) {
                const int c = m_base + 16 * mi + 4 * g + r;
                float v = acc[mi][ni][r] * s_p[c] + t_p[c];
                out[((size_t)bb * 384 + c) * 1024 + n] = v;
            }
        }
    }
}

extern "C" void kernel_launch(void* const* d_in, const int* in_sizes, int n_in,
                              void* d_out, int out_size, void* d_ws, size_t ws_size,
                              hipStream_t stream) {
    const float* x  = (const float*)d_in[0];
    const float* wq = (const float*)d_in[1];
    const float* gq = (const float*)d_in[2];
    const float* bq = (const float*)d_in[3];
    const float* mq = (const float*)d_in[4];
    const float* vq = (const float*)d_in[5];
    const float* wk = (const float*)d_in[6];
    const float* gk = (const float*)d_in[7];
    const float* bk = (const float*)d_in[8];
    const float* mk = (const float*)d_in[9];
    const float* vk = (const float*)d_in[10];
    const float* wv = (const float*)d_in[11];
    const float* gv = (const float*)d_in[12];
    const float* bv = (const float*)d_in[13];
    const float* mv = (const float*)d_in[14];
    const float* vv = (const float*)d_in[15];
    const float* wp = (const float*)d_in[16];
    const float* gp = (const float*)d_in[17];
    const float* bp = (const float*)d_in[18];
    const float* mp = (const float*)d_in[19];
    const float* vp = (const float*)d_in[20];
    float* out = (float*)d_out;

    char* ws = (char*)d_ws;
    size_t off = 0;
    auto alloc = [&](size_t bytes) {
        char* p = ws + off;
        off += (bytes + 255) & ~(size_t)255;
        return p;
    };
    short* xt    = (short*)alloc((size_t)8 * 1024 * 384 * 2);
    short* wqkv  = (short*)alloc((size_t)1024 * 384 * 2);
    short* wpb   = (short*)alloc((size_t)384 * 512 * 2);
    float* s_qkv = (float*)alloc(1024 * 4);
    float* t_qkv = (float*)alloc(1024 * 4);
    float* s_p   = (float*)alloc(384 * 4);
    float* t_p   = (float*)alloc(384 * 4);
    short* Qw    = (short*)alloc((size_t)8 * 8 * 1024 * 32 * 2);
    short* Kw    = (short*)alloc((size_t)8 * 8 * 1024 * 32 * 2);
    short* Vw    = (short*)alloc((size_t)8 * 8 * 64 * 1024 * 2);
    short* Ow    = (short*)alloc((size_t)8 * 1024 * 512 * 2);
    (void)ws_size; (void)in_sizes; (void)n_in; (void)out_size;

    k_prep_x<<<dim3(12, 32, 8), 256, 0, stream>>>(x, xt);
    k_prep_w<<<dim3((1024 * 384 + 384 * 512 + 255) / 256), 256, 0, stream>>>(
        wq, wk, wv, wp, wqkv, wpb,
        gq, bq, mq, vq, gk, bk, mk, vk, gv, bv, mv, vv, gp, bp, mp, vp,
        s_qkv, t_qkv, s_p, t_p);
    k_gemm_qkv<<<dim3(16, 64), 256, 0, stream>>>(wqkv, xt, s_qkv, t_qkv, Qw, Kw, Vw);
    k_attn<<<dim3(1024), 256, 0, stream>>>(Qw, Kw, Vw, Ow);
    k_proj<<<dim3(6, 128), 256, 0, stream>>>(wpb, Ow, s_p, t_p, out);
}

// Round 6
// 115.382 us; speedup vs baseline: 1.3623x; 1.3623x over previous
//
#include <hip/hip_runtime.h>
#include <hip/hip_bf16.h>

#define DEVI __device__ __forceinline__

typedef __attribute__((ext_vector_type(8))) short s16x8;
typedef __attribute__((ext_vector_type(4))) short s16x4;
typedef __attribute__((ext_vector_type(4))) float f32x4;

// ---- problem constants ----
// x: (8, 384, 32, 32); heads=8, dk=32, dv=64; N=1024 tokens; Cqk=256, Cv=512
#define LOG2E 1.4426950408889634f

DEVI short f2bs(float f) {  // fp32 -> bf16 bits (RNE)
    unsigned u = __builtin_bit_cast(unsigned, f);
    unsigned r = (u + 0x7fffu + ((u >> 16) & 1u)) >> 16;
    return (short)r;
}

DEVI f32x4 mfma16(s16x8 a, s16x8 b, f32x4 c) {
    return __builtin_amdgcn_mfma_f32_16x16x32_bf16(a, b, c, 0, 0, 0);
}

// ---------------- prep: x (b,c,n) fp32 -> xt (b,n,c) bf16 ----------------
__global__ __launch_bounds__(256) void k_prep_x(const float* __restrict__ x,
                                                short* __restrict__ xt) {
    __shared__ float tile[32][33];
    const int ct = blockIdx.x, nt = blockIdx.y, b = blockIdx.z;
    const int t = threadIdx.x;
    {
        const int j = t & 31, i0 = (t >> 5) * 4;
        const float* src = x + ((size_t)b * 384 + (size_t)ct * 32) * 1024 + nt * 32;
#pragma unroll
        for (int ii = 0; ii < 4; ++ii)
            tile[i0 + ii][j] = src[(size_t)(i0 + ii) * 1024 + j];
    }
    __syncthreads();
    {
        const int ii = t & 31, j0 = (t >> 5) * 4;
        short* dst = xt + ((size_t)b * 1024 + (size_t)nt * 32) * 384 + ct * 32;
#pragma unroll
        for (int jj = 0; jj < 4; ++jj)
            dst[(size_t)(j0 + jj) * 384 + ii] = f2bs(tile[ii][j0 + jj]);
    }
}

// ---------------- prep: weights fp32 -> bf16, plus BN fold ----------------
// Q-channel BN scale/shift are folded with LOG2E so softmax exp becomes exp2.
__global__ __launch_bounds__(256) void k_prep_w(
    const float* __restrict__ wq, const float* __restrict__ wk,
    const float* __restrict__ wv, const float* __restrict__ wp,
    short* __restrict__ wqkv, short* __restrict__ wpb,
    const float* gq, const float* bq, const float* mq, const float* vq,
    const float* gk, const float* bk, const float* mk, const float* vk,
    const float* gv, const float* bv, const float* mv, const float* vv,
    const float* gp, const float* bp, const float* mp, const float* vp,
    float* s_qkv, float* t_qkv, float* s_p, float* t_p) {
    int i = blockIdx.x * 256 + threadIdx.x;
    if (i < 1024) {
        const float *g, *bb, *mm, *vv_;
        int o = i;
        float post = 1.0f;
        if (i < 256)      { g = gq; bb = bq; mm = mq; vv_ = vq; post = LOG2E; }
        else if (i < 512) { g = gk; bb = bk; mm = mk; vv_ = vk; o = i - 256; }
        else              { g = gv; bb = bv; mm = mv; vv_ = vv; o = i - 512; }
        float s = g[o] * rsqrtf(vv_[o] + 1e-5f);
        s_qkv[i] = s * post;
        t_qkv[i] = (bb[o] - mm[o] * s) * post;
        if (i < 384) {
            float sp = gp[i] * rsqrtf(vp[i] + 1e-5f);
            s_p[i] = sp;
            t_p[i] = bp[i] - mp[i] * sp;
        }
    }
    const int NQKV = 1024 * 384;
    if (i < NQKV) {
        int o = i / 384;
        float v;
        if (o < 256)      v = wq[i];
        else if (o < 512) v = wk[i - 256 * 384];
        else              v = wv[i - 512 * 384];
        wqkv[i] = f2bs(v);
    } else {
        int j = i - NQKV;
        if (j < 384 * 512) wpb[j] = f2bs(wp[j]);
    }
}

// ---------------- QKV GEMM: [1024ch x 384] x [384 x 8192] + BN, layout-split ----------------
// Qw: [b][h][n][32]  Kw: [b][h][m][32]  Vw: [b][h][e][1024]
// Register double-buffered K-loop (prefetch ks+1 before MFMAs on ks).
__global__ __launch_bounds__(256) void k_gemm_qkv(
    const short* __restrict__ wqkv, const short* __restrict__ xt,
    const float* __restrict__ s_qkv, const float* __restrict__ t_qkv,
    short* __restrict__ Qw, short* __restrict__ Kw, short* __restrict__ Vw) {
    const int t = threadIdx.x, lane = t & 63, w = t >> 6;
    const int g = lane >> 4, l15 = lane & 15;
    const int mb = blockIdx.x, jb = blockIdx.y;
    const int m_base = mb * 128 + (w >> 1) * 64;
    const int j_base = jb * 128 + (w & 1) * 64;

    f32x4 acc[4][4];
#pragma unroll
    for (int mi = 0; mi < 4; ++mi)
#pragma unroll
        for (int ni = 0; ni < 4; ++ni) acc[mi][ni] = f32x4{0.f, 0.f, 0.f, 0.f};

    const short* Arow = wqkv + (size_t)(m_base + l15) * 384 + 8 * g;
    const short* Brow = xt + (size_t)(j_base + l15) * 384 + 8 * g;

    s16x8 a[2][4], b[2][4];
#pragma unroll
    for (int i = 0; i < 4; ++i) {
        a[0][i] = *(const s16x8*)(Arow + (size_t)i * 16 * 384);
        b[0][i] = *(const s16x8*)(Brow + (size_t)i * 16 * 384);
    }
#pragma unroll
    for (int ks = 0; ks < 12; ++ks) {
        const int cur = ks & 1, nxt = cur ^ 1;
        if (ks < 11) {
#pragma unroll
            for (int i = 0; i < 4; ++i) {
                a[nxt][i] = *(const s16x8*)(Arow + (size_t)i * 16 * 384 + (ks + 1) * 32);
                b[nxt][i] = *(const s16x8*)(Brow + (size_t)i * 16 * 384 + (ks + 1) * 32);
            }
        }
#pragma unroll
        for (int mi = 0; mi < 4; ++mi)
#pragma unroll
            for (int ni = 0; ni < 4; ++ni)
                acc[mi][ni] = mfma16(a[cur][mi], b[cur][ni], acc[mi][ni]);
    }

#pragma unroll
    for (int mi = 0; mi < 4; ++mi) {
        const int o0 = m_base + 16 * mi;
#pragma unroll
        for (int ni = 0; ni < 4; ++ni) {
            const int j = j_base + 16 * ni + l15;
            const int bb = j >> 10, n = j & 1023;
#pragma unroll
            for (int r = 0; r < 4; ++r) {
                const int o = o0 + 4 * g + r;
                float val = acc[mi][ni][r] * s_qkv[o] + t_qkv[o];
                short bv = f2bs(val);
                if (o0 < 256) {
                    int h = o >> 5, d = o & 31;
                    Qw[(((size_t)bb * 8 + h) * 1024 + n) * 32 + d] = bv;
                } else if (o0 < 512) {
                    int o2 = o - 256;
                    int h = o2 >> 5, d = o2 & 31;
                    Kw[(((size_t)bb * 8 + h) * 1024 + n) * 32 + d] = bv;
                } else {
                    int o2 = o - 512;
                    int h = o2 >> 6, e = o2 & 63;
                    Vw[(((size_t)bb * 8 + h) * 64 + e) * 1024 + n] = bv;
                }
            }
        }
    }
}

// ---------------- attention per (b,h): register-only flash (no-max), LDS-free ----------------
// 32 q-rows per wave, 4 waves/block; grid = 64 bh * 8 rb = 512 blocks, XCD-grouped.
// Trick: QK^T feeds PERMUTED K rows per MFMA (rows m0 + 8*(l15>>2)+(l15&3) + {0,4,32,36})
// so S^T's D-layout == PV's B-operand layout; P never leaves registers.
// PV computed as O^T = mfma(V^T, P); output row e = 4g+r(+16ei), col n = l15(+16niq).
__global__ __launch_bounds__(256, 2) void k_attn(const short* __restrict__ Qw,
                                                 const short* __restrict__ Kw,
                                                 const short* __restrict__ Vw,
                                                 short* __restrict__ Ow) {
    const int t = threadIdx.x, lane = t & 63, w = t >> 6;
    const int g = lane >> 4, l15 = lane & 15;
    // blockIdx.x = (bh&7) + 8*(rb + 8*(bh>>3)) => all 8 rb of one bh on one XCD
    const int low3 = blockIdx.x & 7;
    const int mid = blockIdx.x >> 3;
    const int rb = mid & 7;
    const int bh = ((mid >> 3) << 3) | low3;
    const int n_base = rb * 128 + w * 32;
    const short* Qb = Qw + (size_t)bh * (1024 * 32);
    const short* Kb = Kw + (size_t)bh * (1024 * 32);
    const short* Vb = Vw + (size_t)bh * (64 * 1024);

    s16x8 qf[2];
#pragma unroll
    for (int i = 0; i < 2; ++i)
        qf[i] = *(const s16x8*)(Qb + (size_t)(n_base + 16 * i + l15) * 32 + 8 * g);

    // permuted K base row within each 64-tile
    const int krow = 8 * (l15 >> 2) + (l15 & 3);
    const short* Kbase = Kb + (size_t)krow * 32 + 8 * g;

    f32x4 oacc[2][4];
#pragma unroll
    for (int niq = 0; niq < 2; ++niq)
#pragma unroll
        for (int ei = 0; ei < 4; ++ei) oacc[niq][ei] = f32x4{0.f, 0.f, 0.f, 0.f};
    float l_part[2] = {0.f, 0.f};

#pragma unroll
    for (int mt = 0; mt < 16; ++mt) {
        const int m0 = mt * 64;
        // V^T A-frags: rows e = 16ei+l15, k = m0+32ki+8g..+7
        s16x8 vb[2][4];
#pragma unroll
        for (int ki = 0; ki < 2; ++ki)
#pragma unroll
            for (int ei = 0; ei < 4; ++ei)
                vb[ki][ei] = *(const s16x8*)(Vb + (size_t)(16 * ei + l15) * 1024 + m0 + 32 * ki + 8 * g);
        // permuted K A-frags: mik offsets {0,4,32,36} rows
        s16x8 kf[4];
        kf[0] = *(const s16x8*)(Kbase + (size_t)(m0 + 0) * 32);
        kf[1] = *(const s16x8*)(Kbase + (size_t)(m0 + 4) * 32);
        kf[2] = *(const s16x8*)(Kbase + (size_t)(m0 + 32) * 32);
        kf[3] = *(const s16x8*)(Kbase + (size_t)(m0 + 36) * 32);
        // S^T: st[mik][niq][r] = S[m0 + 8g + r + {0,4,32,36}[mik]][n_base+16niq+l15]
        f32x4 st[4][2];
#pragma unroll
        for (int mik = 0; mik < 4; ++mik)
#pragma unroll
            for (int niq = 0; niq < 2; ++niq)
                st[mik][niq] = mfma16(kf[mik], qf[niq], f32x4{0.f, 0.f, 0.f, 0.f});
        // P = exp2(S'), accumulate l partials, pack to bf16 (stays in registers)
        s16x4 pk[4][2];
#pragma unroll
        for (int mik = 0; mik < 4; ++mik)
#pragma unroll
            for (int niq = 0; niq < 2; ++niq) {
                float p[4];
#pragma unroll
                for (int r = 0; r < 4; ++r) p[r] = __builtin_amdgcn_exp2f(st[mik][niq][r]);
                l_part[niq] += (p[0] + p[1]) + (p[2] + p[3]);
#pragma unroll
                for (int r = 0; r < 4; ++r) pk[mik][niq][r] = f2bs(p[r]);
            }
        // PV: B-frag = concat(pk[2ki], pk[2ki+1]) -- k-slots line up by construction
#pragma unroll
        for (int ki = 0; ki < 2; ++ki)
#pragma unroll
            for (int niq = 0; niq < 2; ++niq) {
                s16x8 pb = __builtin_shufflevector(pk[2 * ki][niq], pk[2 * ki + 1][niq],
                                                   0, 1, 2, 3, 4, 5, 6, 7);
#pragma unroll
                for (int ei = 0; ei < 4; ++ei)
                    oacc[niq][ei] = mfma16(vb[ki][ei], pb, oacc[niq][ei]);
            }
    }

    // l reduction across g groups (butterfly leaves full sum in every lane)
    float li[2];
#pragma unroll
    for (int niq = 0; niq < 2; ++niq) {
        float s = l_part[niq];
        s += __shfl_xor(s, 16, 64);
        s += __shfl_xor(s, 32, 64);
        li[niq] = __builtin_amdgcn_rcpf(s);
    }
    // store O^T fragments: lane holds rows e = 16ei+4g..+3 (consecutive), col n = n_base+16niq+l15
    const int b = bh >> 3, h = bh & 7;
#pragma unroll
    for (int niq = 0; niq < 2; ++niq) {
        const int n = n_base + 16 * niq + l15;
#pragma unroll
        for (int ei = 0; ei < 4; ++ei) {
            s16x4 ov;
#pragma unroll
            for (int r = 0; r < 4; ++r)
                ov[r] = f2bs(fmaxf(oacc[niq][ei][r] * li[niq], 0.f));
            *(s16x4*)(Ow + ((size_t)b * 1024 + n) * 512 + h * 64 + 16 * ei + 4 * g) = ov;
        }
    }
}

// ---------------- proj GEMM: [384 x 512] x [512 x 8192] + BN -> fp32 out ----------------
// Block tile 128m x 64j (waves 2x2, per-wave 64x32); grid (3,128) = 384 blocks.
__global__ __launch_bounds__(256) void k_proj(const short* __restrict__ wpb,
                                              const short* __restrict__ Ow,
                                              const float* __restrict__ s_p,
                                              const float* __restrict__ t_p,
                                              float* __restrict__ out) {
    const int t = threadIdx.x, lane = t & 63, w = t >> 6;
    const int g = lane >> 4, l15 = lane & 15;
    const int mb = blockIdx.x, jb = blockIdx.y;
    const int m_base = mb * 128 + (w >> 1) * 64;
    const int j_base = jb * 64 + (w & 1) * 32;

    f32x4 acc[4][2];
#pragma unroll
    for (int mi = 0; mi < 4; ++mi)
#pragma unroll
        for (int ni = 0; ni < 2; ++ni) acc[mi][ni] = f32x4{0.f, 0.f, 0.f, 0.f};

    const short* Arow = wpb + (size_t)(m_base + l15) * 512 + 8 * g;
    const short* Brow = Ow + (size_t)(j_base + l15) * 512 + 8 * g;

    s16x8 a[2][4], b[2][2];
#pragma unroll
    for (int i = 0; i < 4; ++i) a[0][i] = *(const s16x8*)(Arow + (size_t)i * 16 * 512);
#pragma unroll
    for (int i = 0; i < 2; ++i) b[0][i] = *(const s16x8*)(Brow + (size_t)i * 16 * 512);

#pragma unroll
    for (int ks = 0; ks < 16; ++ks) {
        const int cur = ks & 1, nxt = cur ^ 1;
        if (ks < 15) {
#pragma unroll
            for (int i = 0; i < 4; ++i)
                a[nxt][i] = *(const s16x8*)(Arow + (size_t)i * 16 * 512 + (ks + 1) * 32);
#pragma unroll
            for (int i = 0; i < 2; ++i)
                b[nxt][i] = *(const s16x8*)(Brow + (size_t)i * 16 * 512 + (ks + 1) * 32);
        }
#pragma unroll
        for (int mi = 0; mi < 4; ++mi)
#pragma unroll
            for (int ni = 0; ni < 2; ++ni)
                acc[mi][ni] = mfma16(a[cur][mi], b[cur][ni], acc[mi][ni]);
    }

#pragma unroll
    for (int mi = 0; mi < 4; ++mi) {
#pragma unroll
        for (int ni = 0; ni < 2; ++ni) {
            const int j = j_base + 16 * ni + l15;
            const int bb = j >> 10, n = j & 1023;
#pragma unroll
            for (int r = 0; r < 4; ++r) {
                const int c = m_base + 16 * mi + 4 * g + r;
                float v = acc[mi][ni][r] * s_p[c] + t_p[c];
                out[((size_t)bb * 384 + c) * 1024 + n] = v;
            }
        }
    }
}

extern "C" void kernel_launch(void* const* d_in, const int* in_sizes, int n_in,
                              void* d_out, int out_size, void* d_ws, size_t ws_size,
                              hipStream_t stream) {
    const float* x  = (const float*)d_in[0];
    const float* wq = (const float*)d_in[1];
    const float* gq = (const float*)d_in[2];
    const float* bq = (const float*)d_in[3];
    const float* mq = (const float*)d_in[4];
    const float* vq = (const float*)d_in[5];
    const float* wk = (const float*)d_in[6];
    const float* gk = (const float*)d_in[7];
    const float* bk = (const float*)d_in[8];
    const float* mk = (const float*)d_in[9];
    const float* vk = (const float*)d_in[10];
    const float* wv = (const float*)d_in[11];
    const float* gv = (const float*)d_in[12];
    const float* bv = (const float*)d_in[13];
    const float* mv = (const float*)d_in[14];
    const float* vv = (const float*)d_in[15];
    const float* wp = (const float*)d_in[16];
    const float* gp = (const float*)d_in[17];
    const float* bp = (const float*)d_in[18];
    const float* mp = (const float*)d_in[19];
    const float* vp = (const float*)d_in[20];
    float* out = (float*)d_out;

    char* ws = (char*)d_ws;
    size_t off = 0;
    auto alloc = [&](size_t bytes) {
        char* p = ws + off;
        off += (bytes + 255) & ~(size_t)255;
        return p;
    };
    short* xt    = (short*)alloc((size_t)8 * 1024 * 384 * 2);
    short* wqkv  = (short*)alloc((size_t)1024 * 384 * 2);
    short* wpb   = (short*)alloc((size_t)384 * 512 * 2);
    float* s_qkv = (float*)alloc(1024 * 4);
    float* t_qkv = (float*)alloc(1024 * 4);
    float* s_p   = (float*)alloc(384 * 4);
    float* t_p   = (float*)alloc(384 * 4);
    short* Qw    = (short*)alloc((size_t)8 * 8 * 1024 * 32 * 2);
    short* Kw    = (short*)alloc((size_t)8 * 8 * 1024 * 32 * 2);
    short* Vw    = (short*)alloc((size_t)8 * 8 * 64 * 1024 * 2);
    short* Ow    = (short*)alloc((size_t)8 * 1024 * 512 * 2);
    (void)ws_size; (void)in_sizes; (void)n_in; (void)out_size;

    k_prep_x<<<dim3(12, 32, 8), 256, 0, stream>>>(x, xt);
    k_prep_w<<<dim3((1024 * 384 + 384 * 512 + 255) / 256), 256, 0, stream>>>(
        wq, wk, wv, wp, wqkv, wpb,
        gq, bq, mq, vq, gk, bk, mk, vk, gv, bv, mv, vv, gp, bp, mp, vp,
        s_qkv, t_qkv, s_p, t_p);
    k_gemm_qkv<<<dim3(8, 64), 256, 0, stream>>>(wqkv, xt, s_qkv, t_qkv, Qw, Kw, Vw);
    k_attn<<<dim3(512), 256, 0, stream>>>(Qw, Kw, Vw, Ow);
    k_proj<<<dim3(3, 128), 256, 0, stream>>>(wpb, Ow, s_p, t_p, out);
}